// Round 3
// baseline (123.384 us; speedup 1.0000x reference)
//
#include <hip/hip_runtime.h>

typedef unsigned short u16;
typedef short short8 __attribute__((ext_vector_type(8)));
typedef float floatx4 __attribute__((ext_vector_type(4)));
typedef float floatx2 __attribute__((ext_vector_type(2)));
typedef unsigned int uintx4 __attribute__((ext_vector_type(4)));
typedef unsigned int uintx2 __attribute__((ext_vector_type(2)));
typedef u16 ushortx4 __attribute__((ext_vector_type(4)));

#define FEAT 1024
#define KNB  32

__device__ __forceinline__ u16 f2bf(float f) {
    unsigned u = __float_as_uint(f);
    u += 0x7fffu + ((u >> 16) & 1u);
    return (u16)(u >> 16);
}
__device__ __forceinline__ unsigned pack2bf(float a, float b) {
    return (unsigned)f2bf(a) | ((unsigned)f2bf(b) << 16);
}
__device__ __forceinline__ float softsign(float v) { return v / (1.f + fabsf(v)); }

// async global->LDS, 16B per lane; LDS dest = wave-uniform base + lane*16
__device__ __forceinline__ void gload_lds16(const void* g, void* l) {
    __builtin_amdgcn_global_load_lds(
        (const __attribute__((address_space(1))) unsigned int*)g,
        (__attribute__((address_space(3))) unsigned int*)l, 16, 0, 0);
}

union Frag { uintx4 q; unsigned d[4]; short8 v; };

// LDS overlay: phase1 (layer-1 MFMA) / phase2 (per-node tail) / phase3 (head)
union SMem {
    struct {
        float sS[FEAT];          // 4 KB  S[b] = sum_k nb[n][k][b]
        float sX[FEAT];          // 4 KB  f32 copy of x
        u16   sY[34 * 1024];     // 68 KB bf16 Y rows; reused as Z
    } p1;
    struct {
        float sx2[64 * 64];
        float snb[32 * 64];
        float sx1[64], sS1[64], sadj[4 * 16 * 16], sxa[64];
        float ssc[4], sbi[4], ssc2[4], sbi2[4];
        int   flag;
    } p2;
    struct {
        float sy[64 * 32];
        float sx[64 * 32];
        float ssc[32], sbi[32];
    } p3;
};

// ---------------------------------------------------------------------------
// Mega-kernel v3: staging de-duplication.
// Phase 0: each block converts 4 nb rows -> bf16 (pre-swizzled) into ybf[n]
//          (sc1 stores) + partial column-sum S_part[n][chunk]. Per-node
//          8-block barrier (cnt[64 + n*32]).
// Phase 1: LDS staging = 18x global_load_lds dwordx4 (linear copies of the
//          pre-swizzled image) + 8-way S_part sum. MFMA loop unchanged.
// Phase 2/3 + grid barrier: unchanged from round 2 (verified).
// ws layout (bytes): pws 0..4325376, x22ws ..4333568, cnt ..+16KB,
//                    ybf @4349952 (64*69632), S_part @8806400 (2MB)
// ---------------------------------------------------------------------------
__global__ __launch_bounds__(256, 2) void k_mega(
    const float* __restrict__ xg, const float* __restrict__ nbg,
    const float* __restrict__ w1g, const float* __restrict__ w2g,
    const float* __restrict__ bn1w, const float* __restrict__ bn1b,
    const float* __restrict__ bn2w, const float* __restrict__ bn2b,
    const float* __restrict__ linw, const float* __restrict__ linb,
    float* __restrict__ pws, float* __restrict__ x22ws,
    unsigned int* __restrict__ cnt, u16* __restrict__ ybf,
    float* __restrict__ spart, float* __restrict__ outg)
{
    __shared__ SMem sm;
    float* const sS = sm.p1.sS;
    float* const sX = sm.p1.sX;
    u16*   const sY = sm.p1.sY;

    const int t = threadIdx.x;
    const int bid = blockIdx.x;
    const int n = bid >> 3;
    const int chunk = bid & 7;
    const int chunkbase = chunk * 128;
    const int w = t >> 6;       // wave 0..3
    const int l = t & 63;
    const int m = l & 15;       // MFMA row/col-in-tile
    const int g = l >> 4;       // quad (k-group)

    // ======================= PHASE 0: nb -> bf16 once per node =============
    {
        u16* yb = ybf + (size_t)n * 34816;          // 34 rows * 1024 u16
        const int r0 = chunk * 4 + 1;               // this block's 4 nb rows
        #pragma unroll
        for (int p = 0; p < 2; ++p) {
            int row = r0 + p * 2 + (t >> 7);
            int cc = t & 127;                       // source 16B chunk (8 elems)
            const float* src = nbg + (size_t)(n * KNB + row - 1) * FEAT + cc * 8;
            floatx4 v0 = *(const floatx4*)src;
            floatx4 v1 = *(const floatx4*)(src + 4);
            unsigned long long lo = (unsigned long long)pack2bf(v0[0], v0[1])
                                  | ((unsigned long long)pack2bf(v0[2], v0[3]) << 32);
            unsigned long long hi = (unsigned long long)pack2bf(v1[0], v1[1])
                                  | ((unsigned long long)pack2bf(v1[2], v1[3]) << 32);
            unsigned long long* dst =
                (unsigned long long*)&yb[row * 1024 + ((cc ^ (row & 7)) << 3)];
            __hip_atomic_store(dst,     lo, __ATOMIC_RELAXED, __HIP_MEMORY_SCOPE_AGENT);
            __hip_atomic_store(dst + 1, hi, __ATOMIC_RELAXED, __HIP_MEMORY_SCOPE_AGENT);
        }
        {   // columnar partial S over the 4 rows
            const float* sb = nbg + (size_t)(n * KNB + r0 - 1) * FEAT + t * 4;
            floatx4 a = *(const floatx4*)sb;
            floatx4 b = *(const floatx4*)(sb + FEAT);
            floatx4 c2 = *(const floatx4*)(sb + 2 * FEAT);
            floatx4 d = *(const floatx4*)(sb + 3 * FEAT);
            floatx4 s4 = (a + b) + (c2 + d);
            union { floatx4 f; unsigned long long q[2]; } u; u.f = s4;
            unsigned long long* dst =
                (unsigned long long*)&spart[(size_t)(n * 8 + chunk) * 1024 + t * 4];
            __hip_atomic_store(dst,     u.q[0], __ATOMIC_RELAXED, __HIP_MEMORY_SCOPE_AGENT);
            __hip_atomic_store(dst + 1, u.q[1], __ATOMIC_RELAXED, __HIP_MEMORY_SCOPE_AGENT);
        }
        if (chunk == 0 && t < 128) {                // row 0 = x (identity swizzle)
            const float* src = xg + (size_t)n * FEAT + t * 8;
            floatx4 v0 = *(const floatx4*)src;
            floatx4 v1 = *(const floatx4*)(src + 4);
            unsigned long long lo = (unsigned long long)pack2bf(v0[0], v0[1])
                                  | ((unsigned long long)pack2bf(v0[2], v0[3]) << 32);
            unsigned long long hi = (unsigned long long)pack2bf(v1[0], v1[1])
                                  | ((unsigned long long)pack2bf(v1[2], v1[3]) << 32);
            unsigned long long* dst = (unsigned long long*)&yb[t << 3];
            __hip_atomic_store(dst,     lo, __ATOMIC_RELAXED, __HIP_MEMORY_SCOPE_AGENT);
            __hip_atomic_store(dst + 1, hi, __ATOMIC_RELAXED, __HIP_MEMORY_SCOPE_AGENT);
        }
        if (chunk == 7 && t < 128) {                // row 33 = zeros
            unsigned long long* dst = (unsigned long long*)&yb[33 * 1024 + (t << 3)];
            __hip_atomic_store(dst,     0ull, __ATOMIC_RELAXED, __HIP_MEMORY_SCOPE_AGENT);
            __hip_atomic_store(dst + 1, 0ull, __ATOMIC_RELAXED, __HIP_MEMORY_SCOPE_AGENT);
        }
        // per-node 8-block barrier
        asm volatile("s_waitcnt vmcnt(0)" ::: "memory");
        __syncthreads();
        unsigned int* cN = &cnt[64 + n * 32];
        if (t == 0) {
            __hip_atomic_fetch_add(cN, 1u, __ATOMIC_RELAXED, __HIP_MEMORY_SCOPE_AGENT);
            while (__hip_atomic_load(cN, __ATOMIC_RELAXED, __HIP_MEMORY_SCOPE_AGENT) < 8u)
                __builtin_amdgcn_s_sleep(2);
        }
        __syncthreads();
    }

    // ======================= PHASE 1: layer-1 main =========================
    {   // async-copy pre-swizzled Y image (68 KB) + f32 x (4 KB) into LDS
        const char* ysrc = (const char*)(ybf + (size_t)n * 34816);
        char* ydst = (char*)sY;
        #pragma unroll
        for (int j2 = 0; j2 < 17; ++j2)
            gload_lds16(ysrc + j2 * 4096 + w * 1024 + l * 16,
                        ydst + j2 * 4096 + w * 1024);
        gload_lds16((const char*)(xg + (size_t)n * FEAT) + w * 1024 + l * 16,
                    (char*)sX + w * 1024);
        // sS = sum of the 8 S_part slices
        const float* sp = spart + (size_t)n * 8192 + t * 4;
        floatx4 a = {0.f, 0.f, 0.f, 0.f};
        #pragma unroll
        for (int c2 = 0; c2 < 8; ++c2) a += *(const floatx4*)(sp + c2 * 1024);
        *(floatx4*)&sS[t * 4] = a;
    }

    // per-lane A-side constants (a = chunkbase + w*32 + tile*16 + m)
    const float xa0 = xg[(size_t)n * FEAT + chunkbase + w * 32 + m];
    const float xa1 = xg[(size_t)n * FEAT + chunkbase + w * 32 + 16 + m];
    __syncthreads();
    const float Sa0 = sS[chunkbase + w * 32 + m];
    const float Sa1 = sS[chunkbase + w * 32 + 16 + m];

    const u16* b2base = (m == 0) ? &sY[32 * 1024] : &sY[33 * 1024];  // zeros if m!=0
    const int sw = (m & 7);

    floatx4 acc[2][3];
    #pragma unroll
    for (int i = 0; i < 2; ++i)
        #pragma unroll
        for (int j = 0; j < 3; ++j) { floatx4 z = {0.f, 0.f, 0.f, 0.f}; acc[i][j] = z; }

    const floatx2 vxa0 = {xa0, xa0}, vxa1 = {xa1, xa1};
    const floatx2 vSa0 = {Sa0, Sa0}, vSa1 = {Sa1, Sa1};

    #pragma unroll 2
    for (int s = 0; s < 32; ++s) {
        const int bloc = s * 32 + g * 8;   // this lane's 8 b-columns
        const int cidx = bloc >> 3;        // 16B chunk index

        floatx4 xq0 = *(const floatx4*)&sX[bloc];
        floatx4 xq1 = *(const floatx4*)&sX[bloc + 4];
        floatx4 sq0 = *(const floatx4*)&sS[bloc];
        floatx4 sq1 = *(const floatx4*)&sS[bloc + 4];

        Frag af0, af1;
        #pragma unroll
        for (int p = 0; p < 4; ++p) {
            floatx2 xbp = (p < 2) ? ((p == 0) ? (floatx2){xq0[0], xq0[1]} : (floatx2){xq0[2], xq0[3]})
                                  : ((p == 2) ? (floatx2){xq1[0], xq1[1]} : (floatx2){xq1[2], xq1[3]});
            floatx2 sbp = (p < 2) ? ((p == 0) ? (floatx2){sq0[0], sq0[1]} : (floatx2){sq0[2], sq0[3]})
                                  : ((p == 2) ? (floatx2){sq1[0], sq1[1]} : (floatx2){sq1[2], sq1[3]});
            floatx2 u0 = xbp * vSa0 + sbp * vxa0;   // v_pk_fma path
            floatx2 u1 = xbp * vSa1 + sbp * vxa1;
            uintx2 b0b = __builtin_bit_cast(uintx2, u0);
            uintx2 b1b = __builtin_bit_cast(uintx2, u1);
            af0.d[p] = 0x3F803F80u | (b0b.y & 0x80000000u) | ((b0b.x >> 16) & 0x8000u);
            af1.d[p] = 0x3F803F80u | (b1b.y & 0x80000000u) | ((b1b.x >> 16) & 0x8000u);
        }

        Frag b0, b1, b2;
        b0.q = *(const uintx4*)&sY[ m       * 1024 + ((cidx ^ sw) << 3)];
        b1.q = *(const uintx4*)&sY[(16 + m) * 1024 + ((cidx ^ sw) << 3)];
        b2.q = *(const uintx4*)&b2base[cidx << 3];   // row32 (sw=0) or zero row

        acc[0][0] = __builtin_amdgcn_mfma_f32_16x16x32_bf16(af0.v, b0.v, acc[0][0], 0, 0, 0);
        acc[0][1] = __builtin_amdgcn_mfma_f32_16x16x32_bf16(af0.v, b1.v, acc[0][1], 0, 0, 0);
        acc[0][2] = __builtin_amdgcn_mfma_f32_16x16x32_bf16(af0.v, b2.v, acc[0][2], 0, 0, 0);
        acc[1][0] = __builtin_amdgcn_mfma_f32_16x16x32_bf16(af1.v, b0.v, acc[1][0], 0, 0, 0);
        acc[1][1] = __builtin_amdgcn_mfma_f32_16x16x32_bf16(af1.v, b1.v, acc[1][1], 0, 0, 0);
        acc[1][2] = __builtin_amdgcn_mfma_f32_16x16x32_bf16(af1.v, b2.v, acc[1][2], 0, 0, 0);
    }
    __syncthreads();

    // ---- write Z (bf16) to LDS, layout [j 48][a 128] stride 136 ----
    u16* sZ = sY;
    #pragma unroll
    for (int ti = 0; ti < 2; ++ti)
        #pragma unroll
        for (int jt = 0; jt < 3; ++jt) {
            int j = jt * 16 + m;                  // C col = j
            int aloc = w * 32 + ti * 16 + g * 4;  // C rows = 4 consecutive a
            ushortx4 zz;
            zz.x = f2bf(acc[ti][jt][0]);
            zz.y = f2bf(acc[ti][jt][1]);
            zz.z = f2bf(acc[ti][jt][2]);
            zz.w = f2bf(acc[ti][jt][3]);
            *(ushortx4*)&sZ[j * 136 + aloc] = zz;
        }
    __syncthreads();

    // ---- epilogue: pws[n][chunk][j][o] = sum_{a in chunk} Z[a,j] * W1[o,a] ----
    floatx4 a2[3];
    #pragma unroll
    for (int j = 0; j < 3; ++j) { floatx4 z = {0.f, 0.f, 0.f, 0.f}; a2[j] = z; }
    #pragma unroll
    for (int kc = 0; kc < 4; ++kc) {
        const float* wsrc = w1g + (size_t)(w * 16 + m) * FEAT + chunkbase + kc * 32 + g * 8;
        floatx4 wf0 = *(const floatx4*)wsrc;
        floatx4 wf1 = *(const floatx4*)(wsrc + 4);
        Frag wb;
        wb.d[0] = pack2bf(wf0[0], wf0[1]);
        wb.d[1] = pack2bf(wf0[2], wf0[3]);
        wb.d[2] = pack2bf(wf1[0], wf1[1]);
        wb.d[3] = pack2bf(wf1[2], wf1[3]);
        #pragma unroll
        for (int jt = 0; jt < 3; ++jt) {
            Frag za;
            za.q = *(const uintx4*)&sZ[(jt * 16 + m) * 136 + kc * 32 + g * 8];
            a2[jt] = __builtin_amdgcn_mfma_f32_16x16x32_bf16(za.v, wb.v, a2[jt], 0, 0, 0);
        }
    }
    // sc1 stores (bypass L2 -> coherence point)
    float* pbase = pws + (size_t)(n * 8 + chunk) * 33 * 64;
    #pragma unroll
    for (int jt = 0; jt < 3; ++jt)
        #pragma unroll
        for (int r = 0; r < 4; ++r) {
            int j = jt * 16 + g * 4 + r;
            if (j < 33)
                __hip_atomic_store(&pbase[j * 64 + w * 16 + m], a2[jt][r],
                                   __ATOMIC_RELAXED, __HIP_MEMORY_SCOPE_AGENT);
        }

    // ---- grid barrier: per-wave drain, block barrier, one relaxed add ----
    asm volatile("s_waitcnt vmcnt(0)" ::: "memory");
    __syncthreads();
    if (t == 0)
        __hip_atomic_fetch_add(&cnt[0], 1u, __ATOMIC_RELAXED, __HIP_MEMORY_SCOPE_AGENT);

    // one continuing block per node, spread across XCDs: bid = n*8 + (n&7)
    if ((bid & 7) != (n & 7)) return;

    if (t == 0) {
        while (__hip_atomic_load(&cnt[0], __ATOMIC_RELAXED, __HIP_MEMORY_SCOPE_AGENT) < 512u)
            __builtin_amdgcn_s_sleep(8);
    }
    __syncthreads();   // no acquire fence needed: no stale pws copies can exist

    // ======================= PHASE 2: per-node tail ========================
    float* const sx2  = sm.p2.sx2;
    float* const snb  = sm.p2.snb;
    float* const sx1  = sm.p2.sx1;
    float* const sS1  = sm.p2.sS1;
    float* const sadj = sm.p2.sadj;
    float* const sxa  = sm.p2.sxa;
    float* const ssc  = sm.p2.ssc;
    float* const sbi  = sm.p2.sbi;
    float* const ssc2 = sm.p2.ssc2;
    float* const sbi2 = sm.p2.sbi2;

    // ---- x2 chunk-reduce: 1024 float4 slots (nn*16 + oc), 4 per thread ----
    #pragma unroll
    for (int r = 0; r < 4; ++r) {
        int slot = t + r * 256;
        int nn = slot >> 4, oc = slot & 15;
        const float* p = pws + (size_t)nn * 16896 + oc * 4;   // j = 0
        floatx4 tmp[8];
        #pragma unroll
        for (int c = 0; c < 8; ++c) tmp[c] = *(const floatx4*)(p + c * 2112);
        floatx4 s01 = tmp[0] + tmp[1], s23 = tmp[2] + tmp[3];
        floatx4 s45 = tmp[4] + tmp[5], s67 = tmp[6] + tmp[7];
        *(floatx4*)&sx2[slot * 4] = (s01 + s23) + (s45 + s67);
    }
    // ---- own-node nb chunk-reduce: 512 float4 slots (k*16 + oc), 2 per thread ----
    #pragma unroll
    for (int r = 0; r < 2; ++r) {
        int slot = t + r * 256;
        int k = slot >> 4, oc = slot & 15;
        const float* p = pws + (size_t)n * 16896 + (1 + k) * 64 + oc * 4;
        floatx4 tmp[8];
        #pragma unroll
        for (int c = 0; c < 8; ++c) tmp[c] = *(const floatx4*)(p + c * 2112);
        floatx4 s01 = tmp[0] + tmp[1], s23 = tmp[2] + tmp[3];
        floatx4 s45 = tmp[4] + tmp[5], s67 = tmp[6] + tmp[7];
        *(floatx4*)&snb[slot * 4] = (s01 + s23) + (s45 + s67);
    }
    __syncthreads();
    {   // BN1 x-stats: wave cc reduces channel cc over (nn, f) = 1024 vals
        int cc = t >> 6, l2 = t & 63;
        float s = 0.f, s2 = 0.f;
        #pragma unroll
        for (int i = 0; i < 16; ++i) {
            int idx = l2 * 16 + i;
            int nn = idx >> 4, f = idx & 15;
            float v = sx2[nn * 64 + cc * 16 + f];
            s += v; s2 += v * v;
        }
        // BN1 nb-stats (own node): over (k, f) = 512 vals
        float s3 = 0.f, s4 = 0.f;
        #pragma unroll
        for (int i = 0; i < 8; ++i) {
            int idx = l2 * 8 + i;
            int k = idx >> 4, f = idx & 15;
            float v = snb[k * 64 + cc * 16 + f];
            s3 += v; s4 += v * v;
        }
        #pragma unroll
        for (int off = 32; off > 0; off >>= 1) {
            s  += __shfl_down(s, off);  s2 += __shfl_down(s2, off);
            s3 += __shfl_down(s3, off); s4 += __shfl_down(s4, off);
        }
        if (l2 == 0) {
            float wv = bn1w[cc], bv = bn1b[cc];
            float mean = s * (1.f / 1024.f);
            float var = s2 * (1.f / 1024.f) - mean * mean;
            float rs = rsqrtf(var + 1e-5f);
            ssc[cc] = rs * wv;
            sbi[cc] = bv - mean * rs * wv;
            float mean2 = s3 * (1.f / 512.f);
            float var2 = s4 * (1.f / 512.f) - mean2 * mean2;
            float rs2 = rsqrtf(var2 + 1e-5f);
            ssc2[cc] = rs2 * wv;
            sbi2[cc] = bv - mean2 * rs2 * wv;
        }
    }
    __syncthreads();
    if (t < 64) {
        int cc = t >> 4;
        sx1[t] = softsign(sx2[n * 64 + t] * ssc[cc] + sbi[cc]);
        float a = 0.f;
        for (int k = 0; k < KNB; ++k)
            a += softsign(snb[k * 64 + t] * ssc2[cc] + sbi2[cc]);
        sS1[t] = a;
    }
    __syncthreads();
    {   // exact layer-2 adjacency: one (a,b) pair per thread, channel-coupled denom
        int a = t >> 4, b = t & 15;
        float sc[4]; float den = 1e-7f;
        #pragma unroll
        for (int c = 0; c < 4; ++c) {
            float u = sx1[c * 16 + a] * sS1[c * 16 + b] + sx1[c * 16 + b] * sS1[c * 16 + a];
            float r = sqrtf(fmaxf(fabsf(u), 1e-8f));
            sc[c] = copysignf(r, u);
            den += r;
        }
        float inv = 1.f / den;
        #pragma unroll
        for (int c = 0; c < 4; ++c) sadj[(c * 16 + a) * 16 + b] = sc[c] * inv;
    }
    __syncthreads();
    if (t < 64) {                            // xa2[c][a] = sum_b adj2 * x1
        int cc = t >> 4;
        float a = 0.f;
        #pragma unroll
        for (int b = 0; b < 16; ++b) a += sadj[t * 16 + b] * sx1[cc * 16 + b];
        sxa[t] = a;
    }
    __syncthreads();
    if (t < 32) {                            // x2_2[o] = sum_{c,f} W2[o][c][f] * xa2
        float a = 0.f;
        #pragma unroll
        for (int cf = 0; cf < 64; ++cf) a += w2g[t * 64 + cf] * sxa[cf];
        __hip_atomic_store(&x22ws[n * 32 + t], a,
                           __ATOMIC_RELAXED, __HIP_MEMORY_SCOPE_AGENT);
    }

    // ---- release + elect phase-3 block ----
    asm volatile("s_waitcnt vmcnt(0)" ::: "memory");
    __syncthreads();
    if (t == 0)
        sm.p2.flag = (int)__hip_atomic_fetch_add(&cnt[1], 1u,
                        __ATOMIC_RELAXED, __HIP_MEMORY_SCOPE_AGENT);
    __syncthreads();
    if (sm.p2.flag != 63) return;

    // ======================= PHASE 3: BN2 + head ===========================
    float* const sy   = sm.p3.sy;
    float* const sx3  = sm.p3.sx;
    float* const ssc3 = sm.p3.ssc;
    float* const sbi3 = sm.p3.sbi;

    #pragma unroll
    for (int r = 0; r < 8; ++r) sx3[t + r * 256] = x22ws[t + r * 256];
    __syncthreads();
    if (t < 32) {
        float s = 0.f, s2 = 0.f;
        for (int nn = 0; nn < 64; ++nn) {
            float v = sx3[nn * 32 + t];
            s += v; s2 += v * v;
        }
        float mean = s * (1.f / 64.f);
        float var = s2 * (1.f / 64.f) - mean * mean;
        float rs = rsqrtf(var + 1e-5f);
        float wv = bn2w[t], bv = bn2b[t];
        ssc3[t] = rs * wv;
        sbi3[t] = bv - mean * rs * wv;
    }
    __syncthreads();
    #pragma unroll
    for (int r = 0; r < 8; ++r) {
        int idx = t + r * 256;
        int o = idx & 31;
        sy[idx] = softsign(sx3[idx] * ssc3[o] + sbi3[o]);
    }
    __syncthreads();
    for (int r = 0; r < 3; ++r) {
        int idx = t + r * 256;
        if (idx < 640) {
            int nn = idx / 10, cls = idx % 10;
            float a = linb[cls];
            #pragma unroll
            for (int o = 0; o < 32; ++o) a += sy[nn * 32 + o] * linw[cls * 32 + o];
            outg[idx] = a;
        }
    }
}

extern "C" void kernel_launch(void* const* d_in, const int* in_sizes, int n_in,
                              void* d_out, int out_size, void* d_ws, size_t ws_size,
                              hipStream_t stream) {
    (void)in_sizes; (void)n_in; (void)out_size; (void)ws_size;
    const float* xg   = (const float*)d_in[0];
    const float* nbg  = (const float*)d_in[1];
    const float* w1g  = (const float*)d_in[2];
    const float* w2g  = (const float*)d_in[3];
    const float* bn1w = (const float*)d_in[4];
    const float* bn1b = (const float*)d_in[5];
    const float* bn2w = (const float*)d_in[6];
    const float* bn2b = (const float*)d_in[7];
    const float* linw = (const float*)d_in[8];
    const float* linb = (const float*)d_in[9];

    float* pws   = (float*)d_ws;                               // 4325376 B
    float* x22ws = pws + (size_t)64 * 8 * 33 * 64;             // 8192 B
    unsigned int* cnt = (unsigned int*)((char*)d_ws + 4333568); // 16 KB counters
    u16* ybf     = (u16*)((char*)d_ws + 4349952);              // 64*69632 B
    float* spart = (float*)((char*)d_ws + 8806400);            // 2 MB
    float* outg  = (float*)d_out;

    // workspace is poisoned between runs -> counters need explicit init
    hipMemsetAsync(cnt, 0, 16384, stream);
    k_mega<<<dim3(512), dim3(256), 0, stream>>>(xg, nbg, w1g, w2g, bn1w, bn1b,
                                                bn2w, bn2b, linw, linb,
                                                pws, x22ws, cnt, ybf, spart, outg);
}

// Round 5
// 113.004 us; speedup vs baseline: 1.0919x; 1.0919x over previous
//
#include <hip/hip_runtime.h>

typedef unsigned short u16;
typedef short short8 __attribute__((ext_vector_type(8)));
typedef float floatx4 __attribute__((ext_vector_type(4)));
typedef float floatx2 __attribute__((ext_vector_type(2)));
typedef unsigned int uintx4 __attribute__((ext_vector_type(4)));
typedef unsigned int uintx2 __attribute__((ext_vector_type(2)));
typedef u16 ushortx4 __attribute__((ext_vector_type(4)));

#define FEAT 1024
#define KNB  32

__device__ __forceinline__ u16 f2bf(float f) {
    unsigned u = __float_as_uint(f);
    u += 0x7fffu + ((u >> 16) & 1u);
    return (u16)(u >> 16);
}
__device__ __forceinline__ unsigned pack2bf(float a, float b) {
    return (unsigned)f2bf(a) | ((unsigned)f2bf(b) << 16);
}
__device__ __forceinline__ float softsign(float v) { return v / (1.f + fabsf(v)); }

union Frag { uintx4 q; unsigned d[4]; short8 v; };

// ---------------------------------------------------------------------------
// K2 v2: b-split for occupancy. grid = 1024 (node*16 + half*8 + a-chunk),
// block = 256. Each block stages Y rows 0..33 restricted to its 512-col
// b-half (LDS 38.5 KB -> 4 blocks/CU = 4 waves/SIMD, vs 2 before).
// Z and the W1 epilogue are linear in b, so each block emits a partial
// pws slice; kB sums 16 slices instead of 8.
// Z[a,j] = sum_{b in half} sign(x_a*S_b + x_b*S_a) * Y[j][b]
// ---------------------------------------------------------------------------
__global__ __launch_bounds__(256, 4) void k2_main(
    const float* __restrict__ xg, const float* __restrict__ nbg,
    const float* __restrict__ w1g, float* __restrict__ pws)
{
    __shared__ float sS[512];       // 2 KB  half-cols, full k-sum (k-sequential)
    __shared__ float sX[512];       // 2 KB  f32 x, half-local
    __shared__ float sSa[128];      // 0.5 KB own-chunk full col sums
    __shared__ u16  sY[34 * 512];   // 34 KB bf16 Y rows (half-cols); reused as Z

    const int t = threadIdx.x;
    const int bid = blockIdx.x;
    const int n = bid >> 4;
    const int h = (bid >> 3) & 1;
    const int chunk = bid & 7;
    const int chunkbase = chunk * 128;
    const int hbase = h * 512;
    const int w = t >> 6;       // wave 0..3
    const int l = t & 63;
    const int m = l & 15;       // MFMA row/col-in-tile
    const int g = l >> 4;       // quad (k-group)

    // ---- zero pad row 33 ----
    if (t < 64) { uintx4 z = {0, 0, 0, 0}; *(uintx4*)&sY[33 * 512 + t * 8] = z; }
    // ---- x row (identity swizzle: row&7 == 0) + f32 copy; own-chunk Sa ----
    if (t < 128) {
        floatx4 xv = *(const floatx4*)(xg + (size_t)n * FEAT + hbase + t * 4);
        *(floatx4*)&sX[t * 4] = xv;
        ushortx4 xb4 = {f2bf(xv[0]), f2bf(xv[1]), f2bf(xv[2]), f2bf(xv[3])};
        *(ushortx4*)&sY[t * 4] = xb4;
        // full col sum over k for col chunkbase+t (k-sequential, bit-identical
        // to the original sS order)
        const float* ap = nbg + ((size_t)n * KNB) * FEAT + chunkbase + t;
        float sa = 0.f;
        #pragma unroll
        for (int k = 0; k < KNB; ++k) sa += ap[(size_t)k * FEAT];
        sSa[t] = sa;
    }
    // ---- main staging: each thread owns 2 cols of the half, all 32 rows ----
    {
        const float* nbase = nbg + ((size_t)n * KNB) * FEAT + hbase + t * 2;
        floatx2 sacc = {0.f, 0.f};
        #pragma unroll 8
        for (int k = 0; k < KNB; ++k) {
            floatx2 v = *(const floatx2*)(nbase + (size_t)k * FEAT);
            sacc += v;
            int row = k + 1;
            int c16 = (t >> 2) ^ (row & 7);          // 16B chunk index 0..63
            *(unsigned*)&sY[row * 512 + c16 * 8 + (t & 3) * 2] = pack2bf(v.x, v.y);
        }
        *(floatx2*)&sS[t * 2] = sacc;
    }

    // per-lane A-side constants (a = chunkbase + w*32 + tile*16 + m)
    const float xa0 = xg[(size_t)n * FEAT + chunkbase + w * 32 + m];
    const float xa1 = xg[(size_t)n * FEAT + chunkbase + w * 32 + 16 + m];
    __syncthreads();
    const float Sa0 = sSa[w * 32 + m];
    const float Sa1 = sSa[w * 32 + 16 + m];

    const u16* b2base = (m == 0) ? &sY[32 * 512] : &sY[33 * 512];  // zeros if m!=0
    const int sw = (m & 7);

    floatx4 acc[2][3];
    #pragma unroll
    for (int i = 0; i < 2; ++i)
        #pragma unroll
        for (int j = 0; j < 3; ++j) { floatx4 z = {0.f, 0.f, 0.f, 0.f}; acc[i][j] = z; }

    const floatx2 vxa0 = {xa0, xa0}, vxa1 = {xa1, xa1};
    const floatx2 vSa0 = {Sa0, Sa0}, vSa1 = {Sa1, Sa1};

    #pragma unroll 2
    for (int s = 0; s < 16; ++s) {
        const int bloc = s * 32 + g * 8;   // this lane's 8 b-columns (half-local)
        const int cidx = bloc >> 3;        // 16B chunk index 0..63

        floatx4 xq0 = *(const floatx4*)&sX[bloc];
        floatx4 xq1 = *(const floatx4*)&sX[bloc + 4];
        floatx4 sq0 = *(const floatx4*)&sS[bloc];
        floatx4 sq1 = *(const floatx4*)&sS[bloc + 4];

        Frag af0, af1;
        #pragma unroll
        for (int p = 0; p < 4; ++p) {
            floatx2 xbp = (p < 2) ? ((p == 0) ? (floatx2){xq0[0], xq0[1]} : (floatx2){xq0[2], xq0[3]})
                                  : ((p == 2) ? (floatx2){xq1[0], xq1[1]} : (floatx2){xq1[2], xq1[3]});
            floatx2 sbp = (p < 2) ? ((p == 0) ? (floatx2){sq0[0], sq0[1]} : (floatx2){sq0[2], sq0[3]})
                                  : ((p == 2) ? (floatx2){sq1[0], sq1[1]} : (floatx2){sq1[2], sq1[3]});
            floatx2 u0 = xbp * vSa0 + sbp * vxa0;   // v_pk_fma path
            floatx2 u1 = xbp * vSa1 + sbp * vxa1;
            uintx2 b0b = __builtin_bit_cast(uintx2, u0);
            uintx2 b1b = __builtin_bit_cast(uintx2, u1);
            af0.d[p] = 0x3F803F80u | (b0b.y & 0x80000000u) | ((b0b.x >> 16) & 0x8000u);
            af1.d[p] = 0x3F803F80u | (b1b.y & 0x80000000u) | ((b1b.x >> 16) & 0x8000u);
        }

        Frag b0, b1, b2;
        b0.q = *(const uintx4*)&sY[ m       * 512 + ((cidx ^ sw) << 3)];
        b1.q = *(const uintx4*)&sY[(16 + m) * 512 + ((cidx ^ sw) << 3)];
        b2.q = *(const uintx4*)&b2base[cidx << 3];   // row32 (identity swz) or zeros

        acc[0][0] = __builtin_amdgcn_mfma_f32_16x16x32_bf16(af0.v, b0.v, acc[0][0], 0, 0, 0);
        acc[0][1] = __builtin_amdgcn_mfma_f32_16x16x32_bf16(af0.v, b1.v, acc[0][1], 0, 0, 0);
        acc[0][2] = __builtin_amdgcn_mfma_f32_16x16x32_bf16(af0.v, b2.v, acc[0][2], 0, 0, 0);
        acc[1][0] = __builtin_amdgcn_mfma_f32_16x16x32_bf16(af1.v, b0.v, acc[1][0], 0, 0, 0);
        acc[1][1] = __builtin_amdgcn_mfma_f32_16x16x32_bf16(af1.v, b1.v, acc[1][1], 0, 0, 0);
        acc[1][2] = __builtin_amdgcn_mfma_f32_16x16x32_bf16(af1.v, b2.v, acc[1][2], 0, 0, 0);
    }
    __syncthreads();

    // ---- write partial Z (bf16) to LDS, layout [j 48][a 128] stride 136 ----
    u16* sZ = sY;
    #pragma unroll
    for (int ti = 0; ti < 2; ++ti)
        #pragma unroll
        for (int jt = 0; jt < 3; ++jt) {
            int j = jt * 16 + m;                  // C col = j
            int aloc = w * 32 + ti * 16 + g * 4;  // C rows = 4 consecutive a
            ushortx4 zz;
            zz.x = f2bf(acc[ti][jt][0]);
            zz.y = f2bf(acc[ti][jt][1]);
            zz.z = f2bf(acc[ti][jt][2]);
            zz.w = f2bf(acc[ti][jt][3]);
            *(ushortx4*)&sZ[j * 136 + aloc] = zz;
        }
    __syncthreads();

    // ---- epilogue: pws[n][h][chunk][j][o] = sum_{a in chunk} Z[a,j]*W1[o,a] ----
    floatx4 a2[3];
    #pragma unroll
    for (int j = 0; j < 3; ++j) { floatx4 z = {0.f, 0.f, 0.f, 0.f}; a2[j] = z; }
    #pragma unroll
    for (int kc = 0; kc < 4; ++kc) {
        const float* wsrc = w1g + (size_t)(w * 16 + m) * FEAT + chunkbase + kc * 32 + g * 8;
        floatx4 wf0 = *(const floatx4*)wsrc;
        floatx4 wf1 = *(const floatx4*)(wsrc + 4);
        Frag wb;
        wb.d[0] = pack2bf(wf0[0], wf0[1]);
        wb.d[1] = pack2bf(wf0[2], wf0[3]);
        wb.d[2] = pack2bf(wf1[0], wf1[1]);
        wb.d[3] = pack2bf(wf1[2], wf1[3]);
        #pragma unroll
        for (int jt = 0; jt < 3; ++jt) {
            Frag za;
            za.q = *(const uintx4*)&sZ[(jt * 16 + m) * 136 + kc * 32 + g * 8];
            a2[jt] = __builtin_amdgcn_mfma_f32_16x16x32_bf16(za.v, wb.v, a2[jt], 0, 0, 0);
        }
    }
    float* pbase = pws + (size_t)(n * 16 + h * 8 + chunk) * 33 * 64;
    #pragma unroll
    for (int jt = 0; jt < 3; ++jt)
        #pragma unroll
        for (int r = 0; r < 4; ++r) {
            int j = jt * 16 + g * 4 + r;
            if (j < 33) pbase[j * 64 + w * 16 + m] = a2[jt][r];
        }
}

// ---------------------------------------------------------------------------
// KB: per-node tail (64 blocks). 16-slice chunk-reduce (4 independent chains),
// BN1-x (global stats), x1, nb BN (per n,c), S1, layer-2 adjacency, xa2, W2.
// pws layout: [n][16 slices][j][o] -> offset n*33792 + s*2112 + j*64 + o
// ---------------------------------------------------------------------------
__global__ __launch_bounds__(256, 1) void kB(
    const float* __restrict__ pws, const float* __restrict__ bn1w,
    const float* __restrict__ bn1b, const float* __restrict__ w2g,
    float* __restrict__ x22ws)
{
    __shared__ float sx2[64 * 64];           // [nn][o] all-node x2
    __shared__ float snb[32 * 64];           // [k][o] own-node nb
    __shared__ float sx1[64], sS1[64], sadj[4 * 16 * 16], sxa[64];
    __shared__ float ssc[4], sbi[4], ssc2[4], sbi2[4];
    const int t = threadIdx.x;
    const int n = blockIdx.x;

    // ---- x2 chunk-reduce: 1024 float4 slots (nn*16 + oc), 4 per thread ----
    #pragma unroll
    for (int r = 0; r < 4; ++r) {
        int slot = t + r * 256;
        int nn = slot >> 4, oc = slot & 15;
        const float* p = pws + (size_t)nn * 33792 + oc * 4;   // j = 0
        floatx4 a0 = {0,0,0,0}, a1 = {0,0,0,0}, a2 = {0,0,0,0}, a3 = {0,0,0,0};
        #pragma unroll
        for (int c = 0; c < 4; ++c) {
            a0 += *(const floatx4*)(p + c * 2112);
            a1 += *(const floatx4*)(p + (4 + c) * 2112);
            a2 += *(const floatx4*)(p + (8 + c) * 2112);
            a3 += *(const floatx4*)(p + (12 + c) * 2112);
        }
        *(floatx4*)&sx2[slot * 4] = (a0 + a1) + (a2 + a3);
    }
    // ---- own-node nb chunk-reduce: 512 float4 slots (k*16 + oc), 2 per thread ----
    #pragma unroll
    for (int r = 0; r < 2; ++r) {
        int slot = t + r * 256;
        int k = slot >> 4, oc = slot & 15;
        const float* p = pws + (size_t)n * 33792 + (1 + k) * 64 + oc * 4;
        floatx4 a0 = {0,0,0,0}, a1 = {0,0,0,0}, a2 = {0,0,0,0}, a3 = {0,0,0,0};
        #pragma unroll
        for (int c = 0; c < 4; ++c) {
            a0 += *(const floatx4*)(p + c * 2112);
            a1 += *(const floatx4*)(p + (4 + c) * 2112);
            a2 += *(const floatx4*)(p + (8 + c) * 2112);
            a3 += *(const floatx4*)(p + (12 + c) * 2112);
        }
        *(floatx4*)&snb[slot * 4] = (a0 + a1) + (a2 + a3);
    }
    __syncthreads();
    {   // BN1 x-stats: wave cc reduces channel cc over (nn, f) = 1024 vals
        int cc = t >> 6, l2 = t & 63;
        float s = 0.f, s2 = 0.f;
        #pragma unroll
        for (int i = 0; i < 16; ++i) {
            int idx = l2 * 16 + i;
            int nn = idx >> 4, f = idx & 15;
            float v = sx2[nn * 64 + cc * 16 + f];
            s += v; s2 += v * v;
        }
        // BN1 nb-stats (own node): over (k, f) = 512 vals
        float s3 = 0.f, s4 = 0.f;
        #pragma unroll
        for (int i = 0; i < 8; ++i) {
            int idx = l2 * 8 + i;
            int k = idx >> 4, f = idx & 15;
            float v = snb[k * 64 + cc * 16 + f];
            s3 += v; s4 += v * v;
        }
        #pragma unroll
        for (int off = 32; off > 0; off >>= 1) {
            s  += __shfl_down(s, off);  s2 += __shfl_down(s2, off);
            s3 += __shfl_down(s3, off); s4 += __shfl_down(s4, off);
        }
        if (l2 == 0) {
            float wv = bn1w[cc], bv = bn1b[cc];
            float mean = s * (1.f / 1024.f);
            float var = s2 * (1.f / 1024.f) - mean * mean;
            float rs = rsqrtf(var + 1e-5f);
            ssc[cc] = rs * wv;
            sbi[cc] = bv - mean * rs * wv;
            float mean2 = s3 * (1.f / 512.f);
            float var2 = s4 * (1.f / 512.f) - mean2 * mean2;
            float rs2 = rsqrtf(var2 + 1e-5f);
            ssc2[cc] = rs2 * wv;
            sbi2[cc] = bv - mean2 * rs2 * wv;
        }
    }
    __syncthreads();
    if (t < 64) {
        int cc = t >> 4;
        sx1[t] = softsign(sx2[n * 64 + t] * ssc[cc] + sbi[cc]);
        float a = 0.f;
        for (int k = 0; k < KNB; ++k)
            a += softsign(snb[k * 64 + t] * ssc2[cc] + sbi2[cc]);
        sS1[t] = a;
    }
    __syncthreads();
    {   // exact layer-2 adjacency: one (a,b) pair per thread, channel-coupled denom
        int a = t >> 4, b = t & 15;
        float sc[4]; float den = 1e-7f;
        #pragma unroll
        for (int c = 0; c < 4; ++c) {
            float u = sx1[c * 16 + a] * sS1[c * 16 + b] + sx1[c * 16 + b] * sS1[c * 16 + a];
            float r = sqrtf(fmaxf(fabsf(u), 1e-8f));
            sc[c] = copysignf(r, u);
            den += r;
        }
        float inv = 1.f / den;
        #pragma unroll
        for (int c = 0; c < 4; ++c) sadj[(c * 16 + a) * 16 + b] = sc[c] * inv;
    }
    __syncthreads();
    if (t < 64) {                            // xa2[c][a] = sum_b adj2 * x1
        int cc = t >> 4;
        float a = 0.f;
        #pragma unroll
        for (int b = 0; b < 16; ++b) a += sadj[t * 16 + b] * sx1[cc * 16 + b];
        sxa[t] = a;
    }
    __syncthreads();
    if (t < 32) {                            // x2_2[o] = sum_{c,f} W2[o][c][f] * xa2
        float a = 0.f;
        #pragma unroll
        for (int cf = 0; cf < 64; ++cf) a += w2g[t * 64 + cf] * sxa[cf];
        x22ws[n * 32 + t] = a;
    }
}

// ---------------------------------------------------------------------------
// KC: BN2 (per o over nodes) + softsign + linear head -> f32 logits
// ---------------------------------------------------------------------------
__global__ __launch_bounds__(256) void kC(
    const float* __restrict__ x22ws, const float* __restrict__ bn2w,
    const float* __restrict__ bn2b, const float* __restrict__ linw,
    const float* __restrict__ linb, float* __restrict__ outg)
{
    __shared__ float sy[64 * 32];
    __shared__ float ssc[32], sbi[32];
    __shared__ float sx[64 * 32];
    const int t = threadIdx.x;
    #pragma unroll
    for (int r = 0; r < 8; ++r) sx[t + r * 256] = x22ws[t + r * 256];
    __syncthreads();
    if (t < 32) {
        float s = 0.f, s2 = 0.f;
        for (int nn = 0; nn < 64; ++nn) {
            float v = sx[nn * 32 + t];
            s += v; s2 += v * v;
        }
        float mean = s * (1.f / 64.f);
        float var = s2 * (1.f / 64.f) - mean * mean;
        float rs = rsqrtf(var + 1e-5f);
        float wv = bn2w[t], bv = bn2b[t];
        ssc[t] = rs * wv;
        sbi[t] = bv - mean * rs * wv;
    }
    __syncthreads();
    #pragma unroll
    for (int r = 0; r < 8; ++r) {
        int idx = t + r * 256;
        int o = idx & 31;
        sy[idx] = softsign(sx[idx] * ssc[o] + sbi[o]);
    }
    __syncthreads();
    for (int r = 0; r < 3; ++r) {
        int idx = t + r * 256;
        if (idx < 640) {
            int nn = idx / 10, cls = idx % 10;
            float a = linb[cls];
            #pragma unroll
            for (int o = 0; o < 32; ++o) a += sy[nn * 32 + o] * linw[cls * 32 + o];
            outg[idx] = a;
        }
    }
}

extern "C" void kernel_launch(void* const* d_in, const int* in_sizes, int n_in,
                              void* d_out, int out_size, void* d_ws, size_t ws_size,
                              hipStream_t stream) {
    (void)in_sizes; (void)n_in; (void)out_size; (void)ws_size;
    const float* xg   = (const float*)d_in[0];
    const float* nbg  = (const float*)d_in[1];
    const float* w1g  = (const float*)d_in[2];
    const float* w2g  = (const float*)d_in[3];
    const float* bn1w = (const float*)d_in[4];
    const float* bn1b = (const float*)d_in[5];
    const float* bn2w = (const float*)d_in[6];
    const float* bn2b = (const float*)d_in[7];
    const float* linw = (const float*)d_in[8];
    const float* linb = (const float*)d_in[9];

    float* pws   = (float*)d_ws;                        // [64][16][33][64] f32 partials
    float* x22ws = pws + (size_t)64 * 16 * 33 * 64;     // [64][32]
    float* outg  = (float*)d_out;

    k2_main<<<dim3(1024), dim3(256), 0, stream>>>(xg, nbg, w1g, pws);
    kB<<<dim3(64), dim3(256), 0, stream>>>(pws, bn1w, bn1b, w2g, x22ws);
    kC<<<dim3(1), dim3(256), 0, stream>>>(x22ws, bn2w, bn2b, linw, linb, outg);
}

// Round 6
// 102.919 us; speedup vs baseline: 1.1988x; 1.0980x over previous
//
#include <hip/hip_runtime.h>

typedef unsigned short u16;
typedef short short8 __attribute__((ext_vector_type(8)));
typedef float floatx4 __attribute__((ext_vector_type(4)));
typedef float floatx2 __attribute__((ext_vector_type(2)));
typedef unsigned int uintx4 __attribute__((ext_vector_type(4)));
typedef unsigned int uintx2 __attribute__((ext_vector_type(2)));
typedef u16 ushortx4 __attribute__((ext_vector_type(4)));

#define FEAT 1024
#define KNB  32

__device__ __forceinline__ u16 f2bf(float f) {
    unsigned u = __float_as_uint(f);
    u += 0x7fffu + ((u >> 16) & 1u);
    return (u16)(u >> 16);
}
__device__ __forceinline__ unsigned pack2bf(float a, float b) {
    return (unsigned)f2bf(a) | ((unsigned)f2bf(b) << 16);
}
__device__ __forceinline__ float softsign(float v) { return v / (1.f + fabsf(v)); }

union Frag { uintx4 q; unsigned d[4]; short8 v; };

// ---------------------------------------------------------------------------
// K2: layer-1 main kernel. grid=512, block=256.
// XCD-affinity decode: n = bid & 63, chunk = bid >> 6  ->  all 8 chunk-blocks
// of a node share bid%8 == n%8, i.e. the SAME XCD + L2. The node's 131 KB nb
// image is cold-fetched from HBM once per XCD instead of 8x across XCDs
// (inputs are always cold: the harness re-poisons 256 MiB before each run).
// Everything else is bit-identical to the verified round-0 kernel.
// Z[a,j] = sum_b sign(x_a*S_b + x_b*S_a) * Y[j][b],  Y = [x, nb0..nb31]
// epilogue: pws[n][chunk][j][o] = sum_{a in chunk} Z[a,j] * W1[o,a]
// ---------------------------------------------------------------------------
__global__ __launch_bounds__(256, 2) void k2_main(
    const float* __restrict__ xg, const float* __restrict__ nbg,
    const float* __restrict__ w1g, float* __restrict__ pws)
{
    __shared__ float sS[FEAT];      // 4 KB  S[b] = sum_k nb[n][k][b]  (f32)
    __shared__ float sX[FEAT];      // 4 KB  f32 copy of x (exact xb for sign-gen)
    __shared__ u16  sY[34 * 1024];  // 69.6 KB bf16: row0=x, 1..32=nb, 33=zeros; reused as Z

    const int t = threadIdx.x;
    const int bid = blockIdx.x;
    const int n = bid & 63;         // XCD-affinity: node fixes bid%8
    const int chunk = bid >> 6;
    const int chunkbase = chunk * 128;
    const int w = t >> 6;       // wave 0..3
    const int l = t & 63;
    const int m = l & 15;       // MFMA row/col-in-tile
    const int g = l >> 4;       // quad (k-group)

    // ---- zero pad row 33 ----
    {
        ushortx4 z4 = {0, 0, 0, 0};
        *(ushortx4*)&sY[33 * 1024 + t * 4] = z4;
    }
    // ---- x row: f32 copy + bf16 row 0 (swizzle for row 0 is identity) ----
    {
        floatx4 xv = *(const floatx4*)(xg + (size_t)n * FEAT + t * 4);
        *(floatx4*)&sX[t * 4] = xv;
        ushortx4 xb4 = {f2bf(xv[0]), f2bf(xv[1]), f2bf(xv[2]), f2bf(xv[3])};
        *(ushortx4*)&sY[t * 4] = xb4;
    }
    // ---- single-pass: nb load -> S accumulate + bf16 stage (16B-chunk XOR swizzle) ----
    {
        const float* nbase = nbg + ((size_t)n * KNB) * FEAT + t * 4;
        floatx4 sacc = {0.f, 0.f, 0.f, 0.f};
        #pragma unroll 4
        for (int k = 0; k < KNB; ++k) {
            floatx4 v = *(const floatx4*)(nbase + (size_t)k * FEAT);
            sacc += v;
            int row = k + 1;
            int c16 = (t >> 1) ^ (row & 7);          // 16B chunk index 0..127
            ushortx4 p4 = {f2bf(v[0]), f2bf(v[1]), f2bf(v[2]), f2bf(v[3])};
            *(ushortx4*)&sY[row * 1024 + c16 * 8 + (t & 1) * 4] = p4;
        }
        *(floatx4*)&sS[t * 4] = sacc;
    }

    // per-lane A-side constants (a = chunkbase + w*32 + tile*16 + m)
    const float xa0 = xg[(size_t)n * FEAT + chunkbase + w * 32 + m];
    const float xa1 = xg[(size_t)n * FEAT + chunkbase + w * 32 + 16 + m];
    __syncthreads();
    const float Sa0 = sS[chunkbase + w * 32 + m];
    const float Sa1 = sS[chunkbase + w * 32 + 16 + m];

    const u16* b2base = (m == 0) ? &sY[32 * 1024] : &sY[33 * 1024];  // zeros if m!=0
    const int sw = (m & 7);

    floatx4 acc[2][3];
    #pragma unroll
    for (int i = 0; i < 2; ++i)
        #pragma unroll
        for (int j = 0; j < 3; ++j) { floatx4 z = {0.f, 0.f, 0.f, 0.f}; acc[i][j] = z; }

    const floatx2 vxa0 = {xa0, xa0}, vxa1 = {xa1, xa1};
    const floatx2 vSa0 = {Sa0, Sa0}, vSa1 = {Sa1, Sa1};

    #pragma unroll 2
    for (int s = 0; s < 32; ++s) {
        const int bloc = s * 32 + g * 8;   // this lane's 8 b-columns
        const int cidx = bloc >> 3;        // 16B chunk index

        floatx4 xq0 = *(const floatx4*)&sX[bloc];
        floatx4 xq1 = *(const floatx4*)&sX[bloc + 4];
        floatx4 sq0 = *(const floatx4*)&sS[bloc];
        floatx4 sq1 = *(const floatx4*)&sS[bloc + 4];

        Frag af0, af1;
        #pragma unroll
        for (int p = 0; p < 4; ++p) {
            floatx2 xbp = (p < 2) ? ((p == 0) ? (floatx2){xq0[0], xq0[1]} : (floatx2){xq0[2], xq0[3]})
                                  : ((p == 2) ? (floatx2){xq1[0], xq1[1]} : (floatx2){xq1[2], xq1[3]});
            floatx2 sbp = (p < 2) ? ((p == 0) ? (floatx2){sq0[0], sq0[1]} : (floatx2){sq0[2], sq0[3]})
                                  : ((p == 2) ? (floatx2){sq1[0], sq1[1]} : (floatx2){sq1[2], sq1[3]});
            floatx2 u0 = xbp * vSa0 + sbp * vxa0;   // v_pk_fma path
            floatx2 u1 = xbp * vSa1 + sbp * vxa1;
            uintx2 b0b = __builtin_bit_cast(uintx2, u0);
            uintx2 b1b = __builtin_bit_cast(uintx2, u1);
            af0.d[p] = 0x3F803F80u | (b0b.y & 0x80000000u) | ((b0b.x >> 16) & 0x8000u);
            af1.d[p] = 0x3F803F80u | (b1b.y & 0x80000000u) | ((b1b.x >> 16) & 0x8000u);
        }

        Frag b0, b1, b2;
        b0.q = *(const uintx4*)&sY[ m       * 1024 + ((cidx ^ sw) << 3)];
        b1.q = *(const uintx4*)&sY[(16 + m) * 1024 + ((cidx ^ sw) << 3)];
        b2.q = *(const uintx4*)&b2base[cidx << 3];   // row32 (sw=0) or zero row

        acc[0][0] = __builtin_amdgcn_mfma_f32_16x16x32_bf16(af0.v, b0.v, acc[0][0], 0, 0, 0);
        acc[0][1] = __builtin_amdgcn_mfma_f32_16x16x32_bf16(af0.v, b1.v, acc[0][1], 0, 0, 0);
        acc[0][2] = __builtin_amdgcn_mfma_f32_16x16x32_bf16(af0.v, b2.v, acc[0][2], 0, 0, 0);
        acc[1][0] = __builtin_amdgcn_mfma_f32_16x16x32_bf16(af1.v, b0.v, acc[1][0], 0, 0, 0);
        acc[1][1] = __builtin_amdgcn_mfma_f32_16x16x32_bf16(af1.v, b1.v, acc[1][1], 0, 0, 0);
        acc[1][2] = __builtin_amdgcn_mfma_f32_16x16x32_bf16(af1.v, b2.v, acc[1][2], 0, 0, 0);
    }
    __syncthreads();

    // ---- write Z (bf16) to LDS, layout [j 48][a 128] stride 136 ----
    u16* sZ = sY;
    #pragma unroll
    for (int ti = 0; ti < 2; ++ti)
        #pragma unroll
        for (int jt = 0; jt < 3; ++jt) {
            int j = jt * 16 + m;                  // C col = j
            int aloc = w * 32 + ti * 16 + g * 4;  // C rows = 4 consecutive a
            ushortx4 zz;
            zz.x = f2bf(acc[ti][jt][0]);
            zz.y = f2bf(acc[ti][jt][1]);
            zz.z = f2bf(acc[ti][jt][2]);
            zz.w = f2bf(acc[ti][jt][3]);
            *(ushortx4*)&sZ[j * 136 + aloc] = zz;
        }
    __syncthreads();

    // ---- epilogue: pws[n][chunk][j][o] = sum_{a in chunk} Z[a,j] * W1[o,a] ----
    floatx4 a2[3];
    #pragma unroll
    for (int j = 0; j < 3; ++j) { floatx4 z = {0.f, 0.f, 0.f, 0.f}; a2[j] = z; }
    #pragma unroll
    for (int kc = 0; kc < 4; ++kc) {
        const float* wsrc = w1g + (size_t)(w * 16 + m) * FEAT + chunkbase + kc * 32 + g * 8;
        floatx4 wf0 = *(const floatx4*)wsrc;
        floatx4 wf1 = *(const floatx4*)(wsrc + 4);
        Frag wb;
        wb.d[0] = pack2bf(wf0[0], wf0[1]);
        wb.d[1] = pack2bf(wf0[2], wf0[3]);
        wb.d[2] = pack2bf(wf1[0], wf1[1]);
        wb.d[3] = pack2bf(wf1[2], wf1[3]);
        #pragma unroll
        for (int jt = 0; jt < 3; ++jt) {
            Frag za;
            za.q = *(const uintx4*)&sZ[(jt * 16 + m) * 136 + kc * 32 + g * 8];
            a2[jt] = __builtin_amdgcn_mfma_f32_16x16x32_bf16(za.v, wb.v, a2[jt], 0, 0, 0);
        }
    }
    float* pbase = pws + (size_t)(n * 8 + chunk) * 33 * 64;
    #pragma unroll
    for (int jt = 0; jt < 3; ++jt)
        #pragma unroll
        for (int r = 0; r < 4; ++r) {
            int j = jt * 16 + g * 4 + r;
            if (j < 33) pbase[j * 64 + w * 16 + m] = a2[jt][r];
        }
}

// ---------------------------------------------------------------------------
// KB: per-node tail (64 blocks). Chunk-reduce (float4, batched loads for ILP),
// BN1-x (global stats, redundant per block), x1, nb BN (per n,c), S1,
// layer-2 adjacency, xa2, W2.
// pws layout: [n][chunk][j][o] -> offset n*16896 + chunk*2112 + j*64 + o
// ---------------------------------------------------------------------------
__global__ __launch_bounds__(256, 1) void kB(
    const float* __restrict__ pws, const float* __restrict__ bn1w,
    const float* __restrict__ bn1b, const float* __restrict__ w2g,
    float* __restrict__ x22ws)
{
    __shared__ float sx2[64 * 64];           // [nn][o] all-node x2
    __shared__ float snb[32 * 64];           // [k][o] own-node nb
    __shared__ float sx1[64], sS1[64], sadj[4 * 16 * 16], sxa[64];
    __shared__ float ssc[4], sbi[4], ssc2[4], sbi2[4];
    const int t = threadIdx.x;
    const int n = blockIdx.x;

    // ---- x2 chunk-reduce: 1024 float4 slots (nn*16 + oc), 4 per thread ----
    #pragma unroll
    for (int r = 0; r < 4; ++r) {
        int slot = t + r * 256;
        int nn = slot >> 4, oc = slot & 15;
        const float* p = pws + (size_t)nn * 16896 + oc * 4;   // j = 0
        floatx4 tmp[8];
        #pragma unroll
        for (int c = 0; c < 8; ++c) tmp[c] = *(const floatx4*)(p + c * 2112);
        floatx4 s01 = tmp[0] + tmp[1], s23 = tmp[2] + tmp[3];
        floatx4 s45 = tmp[4] + tmp[5], s67 = tmp[6] + tmp[7];
        *(floatx4*)&sx2[slot * 4] = (s01 + s23) + (s45 + s67);
    }
    // ---- own-node nb chunk-reduce: 512 float4 slots (k*16 + oc), 2 per thread ----
    #pragma unroll
    for (int r = 0; r < 2; ++r) {
        int slot = t + r * 256;
        int k = slot >> 4, oc = slot & 15;
        const float* p = pws + (size_t)n * 16896 + (1 + k) * 64 + oc * 4;
        floatx4 tmp[8];
        #pragma unroll
        for (int c = 0; c < 8; ++c) tmp[c] = *(const floatx4*)(p + c * 2112);
        floatx4 s01 = tmp[0] + tmp[1], s23 = tmp[2] + tmp[3];
        floatx4 s45 = tmp[4] + tmp[5], s67 = tmp[6] + tmp[7];
        *(floatx4*)&snb[slot * 4] = (s01 + s23) + (s45 + s67);
    }
    __syncthreads();
    {   // BN1 x-stats: wave cc reduces channel cc over (nn, f) = 1024 vals
        int cc = t >> 6, l2 = t & 63;
        float s = 0.f, s2 = 0.f;
        #pragma unroll
        for (int i = 0; i < 16; ++i) {
            int idx = l2 * 16 + i;
            int nn = idx >> 4, f = idx & 15;
            float v = sx2[nn * 64 + cc * 16 + f];
            s += v; s2 += v * v;
        }
        // BN1 nb-stats (own node): over (k, f) = 512 vals
        float s3 = 0.f, s4 = 0.f;
        #pragma unroll
        for (int i = 0; i < 8; ++i) {
            int idx = l2 * 8 + i;
            int k = idx >> 4, f = idx & 15;
            float v = snb[k * 64 + cc * 16 + f];
            s3 += v; s4 += v * v;
        }
        #pragma unroll
        for (int off = 32; off > 0; off >>= 1) {
            s  += __shfl_down(s, off);  s2 += __shfl_down(s2, off);
            s3 += __shfl_down(s3, off); s4 += __shfl_down(s4, off);
        }
        if (l2 == 0) {
            float wv = bn1w[cc], bv = bn1b[cc];
            float mean = s * (1.f / 1024.f);
            float var = s2 * (1.f / 1024.f) - mean * mean;
            float rs = rsqrtf(var + 1e-5f);
            ssc[cc] = rs * wv;
            sbi[cc] = bv - mean * rs * wv;
            float mean2 = s3 * (1.f / 512.f);
            float var2 = s4 * (1.f / 512.f) - mean2 * mean2;
            float rs2 = rsqrtf(var2 + 1e-5f);
            ssc2[cc] = rs2 * wv;
            sbi2[cc] = bv - mean2 * rs2 * wv;
        }
    }
    __syncthreads();
    if (t < 64) {
        int cc = t >> 4;
        sx1[t] = softsign(sx2[n * 64 + t] * ssc[cc] + sbi[cc]);
        float a = 0.f;
        for (int k = 0; k < KNB; ++k)
            a += softsign(snb[k * 64 + t] * ssc2[cc] + sbi2[cc]);
        sS1[t] = a;
    }
    __syncthreads();
    {   // exact layer-2 adjacency: one (a,b) pair per thread, channel-coupled denom
        int a = t >> 4, b = t & 15;
        float sc[4]; float den = 1e-7f;
        #pragma unroll
        for (int c = 0; c < 4; ++c) {
            float u = sx1[c * 16 + a] * sS1[c * 16 + b] + sx1[c * 16 + b] * sS1[c * 16 + a];
            float r = sqrtf(fmaxf(fabsf(u), 1e-8f));
            sc[c] = copysignf(r, u);
            den += r;
        }
        float inv = 1.f / den;
        #pragma unroll
        for (int c = 0; c < 4; ++c) sadj[(c * 16 + a) * 16 + b] = sc[c] * inv;
    }
    __syncthreads();
    if (t < 64) {                            // xa2[c][a] = sum_b adj2 * x1
        int cc = t >> 4;
        float a = 0.f;
        #pragma unroll
        for (int b = 0; b < 16; ++b) a += sadj[t * 16 + b] * sx1[cc * 16 + b];
        sxa[t] = a;
    }
    __syncthreads();
    if (t < 32) {                            // x2_2[o] = sum_{c,f} W2[o][c][f] * xa2
        float a = 0.f;
        #pragma unroll
        for (int cf = 0; cf < 64; ++cf) a += w2g[t * 64 + cf] * sxa[cf];
        x22ws[n * 32 + t] = a;
    }
}

// ---------------------------------------------------------------------------
// KC: BN2 (per o over nodes) + softsign + linear head -> f32 logits
// ---------------------------------------------------------------------------
__global__ __launch_bounds__(256) void kC(
    const float* __restrict__ x22ws, const float* __restrict__ bn2w,
    const float* __restrict__ bn2b, const float* __restrict__ linw,
    const float* __restrict__ linb, float* __restrict__ outg)
{
    __shared__ float sy[64 * 32];
    __shared__ float ssc[32], sbi[32];
    __shared__ float sx[64 * 32];
    const int t = threadIdx.x;
    #pragma unroll
    for (int r = 0; r < 8; ++r) sx[t + r * 256] = x22ws[t + r * 256];
    __syncthreads();
    if (t < 32) {
        float s = 0.f, s2 = 0.f;
        for (int nn = 0; nn < 64; ++nn) {
            float v = sx[nn * 32 + t];
            s += v; s2 += v * v;
        }
        float mean = s * (1.f / 64.f);
        float var = s2 * (1.f / 64.f) - mean * mean;
        float rs = rsqrtf(var + 1e-5f);
        float wv = bn2w[t], bv = bn2b[t];
        ssc[t] = rs * wv;
        sbi[t] = bv - mean * rs * wv;
    }
    __syncthreads();
    #pragma unroll
    for (int r = 0; r < 8; ++r) {
        int idx = t + r * 256;
        int o = idx & 31;
        sy[idx] = softsign(sx[idx] * ssc[o] + sbi[o]);
    }
    __syncthreads();
    for (int r = 0; r < 3; ++r) {
        int idx = t + r * 256;
        if (idx < 640) {
            int nn = idx / 10, cls = idx % 10;
            float a = linb[cls];
            #pragma unroll
            for (int o = 0; o < 32; ++o) a += sy[nn * 32 + o] * linw[cls * 32 + o];
            outg[idx] = a;
        }
    }
}

extern "C" void kernel_launch(void* const* d_in, const int* in_sizes, int n_in,
                              void* d_out, int out_size, void* d_ws, size_t ws_size,
                              hipStream_t stream) {
    (void)in_sizes; (void)n_in; (void)out_size; (void)ws_size;
    const float* xg   = (const float*)d_in[0];
    const float* nbg  = (const float*)d_in[1];
    const float* w1g  = (const float*)d_in[2];
    const float* w2g  = (const float*)d_in[3];
    const float* bn1w = (const float*)d_in[4];
    const float* bn1b = (const float*)d_in[5];
    const float* bn2w = (const float*)d_in[6];
    const float* bn2b = (const float*)d_in[7];
    const float* linw = (const float*)d_in[8];
    const float* linb = (const float*)d_in[9];

    float* pws   = (float*)d_ws;                       // [64][8][33][64] f32 partials
    float* x22ws = pws + (size_t)64 * 8 * 33 * 64;     // [64][32]
    float* outg  = (float*)d_out;

    k2_main<<<dim3(512), dim3(256), 0, stream>>>(xg, nbg, w1g, pws);
    kB<<<dim3(64), dim3(256), 0, stream>>>(pws, bn1w, bn1b, w2g, x22ws);
    kC<<<dim3(1), dim3(256), 0, stream>>>(x22ws, bn2w, bn2b, linw, linb, outg);
}